// Round 6
// baseline (442.339 us; speedup 1.0000x reference)
//
#include <hip/hip_runtime.h>
#include <stdint.h>
#include <stddef.h>

#define NN 50000
#define NE 800000
#define DD 128
#define NL 4
#define NG 512
#define NC 10
#define NB 196           // buckets of 256 dest nodes: ceil(50000/256)
#define BCAP 5056        // per-bucket capacity (mean 4096, sd ~64 -> 15 sd margin)

using short8 = __attribute__((ext_vector_type(8))) short;
using f32x4  = __attribute__((ext_vector_type(4))) float;

__device__ __forceinline__ float bf2f(unsigned short u) {
  union { unsigned int i; float f; } c; c.i = ((unsigned int)u) << 16; return c.f;
}
__device__ __forceinline__ unsigned short f2bf(float f) {
  union { unsigned int i; float f; } c; c.f = f;
  unsigned int i = c.i;
  return (unsigned short)((i + 0x7FFFu + ((i >> 16) & 1u)) >> 16);
}
__device__ __forceinline__ unsigned int pack2(float a, float b) {
  return (unsigned int)f2bf(a) | ((unsigned int)f2bf(b) << 16);
}
__device__ __forceinline__ void acc8(float* a, uint4 p) {
  a[0] += bf2f((unsigned short)(p.x & 0xffffu)); a[1] += bf2f((unsigned short)(p.x >> 16));
  a[2] += bf2f((unsigned short)(p.y & 0xffffu)); a[3] += bf2f((unsigned short)(p.y >> 16));
  a[4] += bf2f((unsigned short)(p.z & 0xffffu)); a[5] += bf2f((unsigned short)(p.z >> 16));
  a[6] += bf2f((unsigned short)(p.w & 0xffffu)); a[7] += bf2f((unsigned short)(p.w >> 16));
}

// ---------------- pass1a: bucket histogram (LDS-aggregated) ----------------
__global__ __launch_bounds__(1024) void p1a_k(const int* __restrict__ ecol,
                                              int* __restrict__ hist) {
  __shared__ int lh[NB];
  int tid = threadIdx.x;
  if (tid < NB) lh[tid] = 0;
  __syncthreads();
  int e0 = blockIdx.x * 4096 + tid;
#pragma unroll
  for (int j = 0; j < 4; ++j) {
    int e = e0 + j * 1024;
    if (e < NE) atomicAdd(&lh[ecol[e] >> 8], 1);
  }
  __syncthreads();
  if (tid < NB && lh[tid] > 0) atomicAdd(&hist[tid], lh[tid]);
}

// ---------------- scan196: bucket bases, init cursors ----------------
__global__ __launch_bounds__(256) void scanb_k(const int* __restrict__ hist,
                                               int* __restrict__ ebase,
                                               int* __restrict__ cursor,
                                               int* __restrict__ csr_ptr) {
  __shared__ int sc[256];
  int t = threadIdx.x;
  int h = (t < NB) ? hist[t] : 0;
  sc[t] = h; __syncthreads();
  for (int off = 1; off < 256; off <<= 1) {
    int v = (t >= off) ? sc[t - off] : 0;
    __syncthreads();
    sc[t] += v;
    __syncthreads();
  }
  if (t < NB) { ebase[t] = sc[t] - h; cursor[t] = sc[t] - h; }
  if (t == NB - 1) ebase[NB] = sc[t];
  if (t == 0) csr_ptr[NN] = NE;
}

// ---------------- pass1b: place packed edges into bucket regions ----------------
__global__ __launch_bounds__(1024) void p1b_k(const int* __restrict__ erow,
                                              const int* __restrict__ ecol,
                                              int* __restrict__ cursor,
                                              unsigned int* __restrict__ ebuf) {
  __shared__ int lcnt[NB], gb[NB];
  int tid = threadIdx.x;
  if (tid < NB) lcnt[tid] = 0;
  __syncthreads();
  int e0 = blockIdx.x * 4096 + tid;
  int bk[4], sl[4]; unsigned int pk[4];
#pragma unroll
  for (int j = 0; j < 4; ++j) {
    int e = e0 + j * 1024;
    bk[j] = -1;
    if (e < NE) {
      int d = ecol[e], s = erow[e];
      bk[j] = d >> 8;
      pk[j] = ((unsigned int)(d & 255) << 16) | (unsigned int)s;
      sl[j] = atomicAdd(&lcnt[bk[j]], 1);
    }
  }
  __syncthreads();
  if (tid < NB) {
    int c = lcnt[tid];
    gb[tid] = c ? atomicAdd(&cursor[tid], c) : 0;
  }
  __syncthreads();
#pragma unroll
  for (int j = 0; j < 4; ++j)
    if (bk[j] >= 0) ebuf[gb[bk[j]] + sl[j]] = pk[j];
}

// ---------------- pass2: per-bucket counting sort + dinv + x->bf16*dinv ----------------
__global__ __launch_bounds__(1024) void p2_k(const unsigned int* __restrict__ ebuf,
                                             const int* __restrict__ ebase,
                                             const float* __restrict__ x,
                                             int* __restrict__ csr_ptr,
                                             int* __restrict__ csr_src,
                                             float* __restrict__ dinv,
                                             unsigned short* __restrict__ xb) {
  __shared__ unsigned int pr[BCAP];
  __shared__ int srcb[BCAP];
  __shared__ int hist_s[256], scn[256], lcur[256];
  __shared__ float dinv_s[256];
  int b = blockIdx.x, tid = threadIdx.x;
  int beg = ebase[b];
  int cnt = ebase[b + 1] - beg;
  if (cnt > BCAP) cnt = BCAP;   // safety clamp (never hit for this dataset)

  if (tid < 256) hist_s[tid] = 0;
  __syncthreads();
  for (int i = tid; i < cnt; i += 1024) {
    unsigned int p = ebuf[beg + i];
    pr[i] = p;
    atomicAdd(&hist_s[p >> 16], 1);
  }
  __syncthreads();
  if (tid < 256) scn[tid] = hist_s[tid];
  __syncthreads();
  for (int off = 1; off < 256; off <<= 1) {
    int v = (tid < 256 && tid >= off) ? scn[tid - off] : 0;
    __syncthreads();
    if (tid < 256) scn[tid] += v;
    __syncthreads();
  }
  if (tid < 256) {
    int ex = scn[tid] - hist_s[tid];
    lcur[tid] = ex;
    int V = b * 256 + tid;
    if (V < NN) {
      csr_ptr[V] = beg + ex;
      float dv = rsqrtf((float)(hist_s[tid] + 1));
      dinv[V] = dv;
      dinv_s[tid] = dv;
    }
  }
  __syncthreads();
  for (int i = tid; i < cnt; i += 1024) {
    unsigned int p = pr[i];
    int pos = atomicAdd(&lcur[p >> 16], 1);
    srcb[pos] = (int)(p & 0xFFFFu);
  }
  __syncthreads();
  for (int i = tid; i < cnt; i += 1024) csr_src[beg + i] = srcb[i];

  // x -> bf16 pre-scaled by dinv for this bucket's nodes
  for (int i4 = tid; i4 < 256 * 32; i4 += 1024) {
    int vl = i4 >> 5;
    int V = b * 256 + vl;
    if (V < NN) {
      float d = dinv_s[vl];
      f32x4 vx = *((const f32x4*)(x + (size_t)V * DD) + (i4 & 31));
      uint2 o;
      o.x = pack2(vx[0] * d, vx[1] * d);
      o.y = pack2(vx[2] * d, vx[3] * d);
      *((uint2*)(xb + (size_t)V * DD) + (i4 & 31)) = o;
    }
  }
}

// ---------------- gptr: graph boundaries from sorted batch ----------------
__global__ void gptr_k(const int* __restrict__ batch, int* __restrict__ gptr) {
  int i = blockIdx.x * 256 + threadIdx.x;
  if (i >= NN) return;
  int b  = batch[i];
  int bp = (i == 0) ? -1 : batch[i - 1];
  for (int g = bp + 1; g <= b; ++g) gptr[g] = i;
  if (i == NN - 1) { for (int g = b + 1; g <= NG; ++g) gptr[g] = NN; }
}

// ---------------- fused GCN layer: gather-agg (LDS) + MFMA GEMM + bias + relu ----------------
// hs: [NN,128] bf16 pre-scaled by dinv. out: relu((dinv_v*(hs_v+sum hs_s)) @ W + b),
// times dinv_v again unless last (pre-scale for next layer's gather).
// Block = 256 threads = 4 waves; 64 dest rows/block.
// Gather: 16 quarter-waves x 4 nodes each, 4-way edge unroll -> 4 outstanding 16B gathers/lane.
__global__ __launch_bounds__(256) void layer_k(const unsigned short* __restrict__ hs,
                                               const float* __restrict__ W,
                                               const float* __restrict__ bias,
                                               unsigned short* __restrict__ out,
                                               const int* __restrict__ csr_ptr,
                                               const int* __restrict__ csr_src,
                                               const float* __restrict__ dinv,
                                               int last) {
  __shared__ unsigned short Wt[128][136];    // transposed W (bf16), +8 pad
  __shared__ unsigned short aggS[64][136];   // gathered rows (bf16), +8 pad (272B row, 16B-aligned)
  int tid = threadIdx.x;

  // stage W^T first so its latency hides under the gather
  for (int i = tid; i < 128 * 128; i += 256) {
    int k = i >> 7, n = i & 127;
    Wt[n][k] = f2bf(W[i]);
  }

  int row0 = blockIdx.x * 64;
  int qi = tid >> 4, r = tid & 15;           // quarter-wave id, lane-in-quarter
  const uint4* rows = (const uint4*)hs;      // row v = rows[v*16 + r]

#pragma unroll
  for (int j = 0; j < 4; ++j) {
    int nb = qi * 4 + j;
    int v = row0 + nb;
    float a[8] = {0.f, 0.f, 0.f, 0.f, 0.f, 0.f, 0.f, 0.f};
    if (v < NN) {
      acc8(a, rows[(size_t)v * 16 + r]);     // self term
      int e = csr_ptr[v], end = csr_ptr[v + 1];
      for (; e + 3 < end; e += 4) {
        int s0 = csr_src[e], s1 = csr_src[e + 1], s2 = csr_src[e + 2], s3 = csr_src[e + 3];
        uint4 p0 = rows[(size_t)s0 * 16 + r];
        uint4 p1 = rows[(size_t)s1 * 16 + r];
        uint4 p2 = rows[(size_t)s2 * 16 + r];
        uint4 p3 = rows[(size_t)s3 * 16 + r];
        acc8(a, p0); acc8(a, p1); acc8(a, p2); acc8(a, p3);
      }
      for (; e < end; ++e) acc8(a, rows[(size_t)csr_src[e] * 16 + r]);
      float dv = dinv[v];
#pragma unroll
      for (int t = 0; t < 8; ++t) a[t] *= dv;
    }
    uint4 o;
    o.x = pack2(a[0], a[1]); o.y = pack2(a[2], a[3]);
    o.z = pack2(a[4], a[5]); o.w = pack2(a[6], a[7]);
    *(uint4*)&aggS[nb][r * 8] = o;
  }
  __syncthreads();

  // MFMA phase: wave w handles rows row0+16w .. +15, all 128 cols
  int wave = tid >> 6, lane = tid & 63;
  int q = lane >> 4, rr16 = lane & 15;
  int wrow0 = row0 + wave * 16;

  short8 afrag[4];
#pragma unroll
  for (int ks = 0; ks < 4; ++ks)
    afrag[ks] = *(const short8*)(&aggS[wave * 16 + rr16][ks * 32 + q * 8]);

  f32x4 acc[8];
#pragma unroll
  for (int ct = 0; ct < 8; ++ct) acc[ct] = (f32x4){0.f, 0.f, 0.f, 0.f};

#pragma unroll
  for (int ks = 0; ks < 4; ++ks) {
#pragma unroll
    for (int ct = 0; ct < 8; ++ct) {
      short8 bfrag = *(const short8*)(&Wt[ct * 16 + rr16][ks * 32 + q * 8]);
      acc[ct] = __builtin_amdgcn_mfma_f32_16x16x32_bf16(afrag[ks], bfrag, acc[ct], 0, 0, 0);
    }
  }

  // C/D layout: col = ct*16 + rr16, row = wrow0 + q*4 + reg
  int orow = wrow0 + q * 4;
  float sc[4];
#pragma unroll
  for (int reg = 0; reg < 4; ++reg) {
    int rr = orow + reg;
    sc[reg] = (!last && rr < NN) ? dinv[rr] : 1.f;
  }
#pragma unroll
  for (int ct = 0; ct < 8; ++ct) {
    int coln = ct * 16 + rr16;
    float bc = bias[coln];
#pragma unroll
    for (int reg = 0; reg < 4; ++reg) {
      int rr = orow + reg;
      if (rr < NN) {
        float val = fmaxf(acc[ct][reg] + bc, 0.f) * sc[reg];
        out[(size_t)rr * DD + coln] = f2bf(val);
      }
    }
  }
}

// ---------------- pooling ----------------
__global__ __launch_bounds__(128) void pool_k(const unsigned short* __restrict__ h,
                                              const int* __restrict__ gptr,
                                              float* __restrict__ gpool) {
  int g = blockIdx.x, t = threadIdx.x;
  int beg = gptr[g], end = gptr[g + 1];
  float acc = 0.f;
  for (int v = beg; v < end; ++v) acc += bf2f(h[(size_t)v * DD + t]);
  gpool[g * DD + t] = acc;
}

// ---------------- MLP head ----------------
__global__ __launch_bounds__(128) void mlp_k(const float* __restrict__ gpool,
                                             const float* __restrict__ W1,
                                             const float* __restrict__ b1,
                                             const float* __restrict__ W2,
                                             const float* __restrict__ b2,
                                             const float* __restrict__ W3,
                                             const float* __restrict__ b3,
                                             float* __restrict__ out) {
  __shared__ float s_g[128], s_h1[128], s_h2[64];
  int g = blockIdx.x, t = threadIdx.x;
  s_g[t] = gpool[g * DD + t];
  __syncthreads();
  {
    float a = b1[t];
    for (int k = 0; k < 128; ++k) a += s_g[k] * W1[k * 128 + t];
    s_h1[t] = fmaxf(a, 0.f);
  }
  __syncthreads();
  if (t < 64) {
    float a = b2[t];
    for (int k = 0; k < 128; ++k) a += s_h1[k] * W2[k * 64 + t];
    s_h2[t] = fmaxf(a, 0.f);
  }
  __syncthreads();
  if (t < NC) {
    float a = b3[t];
    for (int k = 0; k < 64; ++k) a += s_h2[k] * W3[k * NC + t];
    out[g * NC + t] = a;
  }
}

// ---------------- launch ----------------

extern "C" void kernel_launch(void* const* d_in, const int* in_sizes, int n_in,
                              void* d_out, int out_size, void* d_ws, size_t ws_size,
                              hipStream_t stream) {
  const float* x     = (const float*)d_in[0];
  const int*   ei    = (const int*)d_in[1];
  const int*   batch = (const int*)d_in[2];
  const float* Wc    = (const float*)d_in[3];
  const float* bc    = (const float*)d_in[4];
  const float* W1    = (const float*)d_in[5];
  const float* b1    = (const float*)d_in[6];
  const float* W2    = (const float*)d_in[7];
  const float* b2    = (const float*)d_in[8];
  const float* W3    = (const float*)d_in[9];
  const float* b3    = (const float*)d_in[10];
  float* out = (float*)d_out;

  const int* erow = ei;        // edge_index[0] (source)
  const int* ecol = ei + NE;   // edge_index[1] (dest)

  char* w = (char*)d_ws;
  int*   hist    = (int*)w;    w += NB * 4;          // memset 0
  int*   cursor  = (int*)w;    w += NB * 4;          // memset 0 (overwritten by scanb)
  int*   ebase   = (int*)w;    w += (NB + 4) * 4;
  int*   csr_ptr = (int*)w;    w += (size_t)(NN + 4) * 4;
  int*   gptr    = (int*)w;    w += (NG + 4) * 4;
  int*   csr_src = (int*)w;    w += (size_t)NE * 4;
  float* dinv    = (float*)w;  w += (size_t)NN * 4;
  float* gpool   = (float*)w;  w += (size_t)NG * DD * 4;
  w = (char*)(((uintptr_t)w + 255) & ~(uintptr_t)255);
  unsigned short* xb = (unsigned short*)w; w += (size_t)NN * DD * 2;
  unsigned short* hA = (unsigned short*)w; w += (size_t)NN * DD * 2;
  unsigned short* hB = (unsigned short*)w; w += (size_t)NN * DD * 2;
  unsigned int* ebuf = (unsigned int*)hA;  // alias: ebuf dead before layer 0 writes hA

  hipMemsetAsync(d_ws, 0, NB * 2 * 4, stream);   // hist + cursor

  p1a_k  <<<NB, 1024, 0, stream>>>(ecol, hist);
  scanb_k<<<1, 256, 0, stream>>>(hist, ebase, cursor, csr_ptr);
  p1b_k  <<<NB, 1024, 0, stream>>>(erow, ecol, cursor, ebuf);
  p2_k   <<<NB, 1024, 0, stream>>>(ebuf, ebase, x, csr_ptr, csr_src, dinv, xb);
  gptr_k <<<(NN + 255) / 256, 256, 0, stream>>>(batch, gptr);

  const int layerGrid = (NN + 63) / 64;

  // ping-pong: xb -> hA -> hB -> hA -> hB (fused kernel can't write its gather input)
  const unsigned short* src[NL] = {xb, hA, hB, hA};
  unsigned short*       dst[NL] = {hA, hB, hA, hB};
  for (int l = 0; l < NL; ++l) {
    layer_k<<<layerGrid, 256, 0, stream>>>(src[l], Wc + (size_t)l * DD * DD,
                                           bc + (size_t)l * DD, dst[l],
                                           csr_ptr, csr_src, dinv, (l == NL - 1) ? 1 : 0);
  }

  pool_k<<<NG, 128, 0, stream>>>(dst[NL - 1], gptr, gpool);
  mlp_k <<<NG, 128, 0, stream>>>(gpool, W1, b1, W2, b2, W3, b3, out);

  (void)in_sizes; (void)n_in; (void)out_size; (void)ws_size;
}

// Round 7
// 365.642 us; speedup vs baseline: 1.2098x; 1.2098x over previous
//
#include <hip/hip_runtime.h>
#include <stdint.h>
#include <stddef.h>

#define NN 50000
#define NE 800000
#define DD 128
#define NL 4
#define NG 512
#define NC 10
#define NB 196           // buckets of 256 dest nodes: ceil(50000/256)
#define BCAP 5056        // per-bucket capacity (mean 4096, sd ~64 -> 15 sd margin)

using short8 = __attribute__((ext_vector_type(8))) short;
using f32x4  = __attribute__((ext_vector_type(4))) float;

__device__ __forceinline__ float bf2f(unsigned short u) {
  union { unsigned int i; float f; } c; c.i = ((unsigned int)u) << 16; return c.f;
}
__device__ __forceinline__ unsigned short f2bf(float f) {
  union { unsigned int i; float f; } c; c.f = f;
  unsigned int i = c.i;
  return (unsigned short)((i + 0x7FFFu + ((i >> 16) & 1u)) >> 16);
}
__device__ __forceinline__ unsigned int pack2(float a, float b) {
  return (unsigned int)f2bf(a) | ((unsigned int)f2bf(b) << 16);
}
__device__ __forceinline__ void acc8(float* a, uint4 p) {
  a[0] += bf2f((unsigned short)(p.x & 0xffffu)); a[1] += bf2f((unsigned short)(p.x >> 16));
  a[2] += bf2f((unsigned short)(p.y & 0xffffu)); a[3] += bf2f((unsigned short)(p.y >> 16));
  a[4] += bf2f((unsigned short)(p.z & 0xffffu)); a[5] += bf2f((unsigned short)(p.z >> 16));
  a[6] += bf2f((unsigned short)(p.w & 0xffffu)); a[7] += bf2f((unsigned short)(p.w >> 16));
}

// ---------------- pass1a: bucket histogram (LDS-aggregated) ----------------
__global__ __launch_bounds__(1024) void p1a_k(const int* __restrict__ ecol,
                                              int* __restrict__ hist) {
  __shared__ int lh[NB];
  int tid = threadIdx.x;
  if (tid < NB) lh[tid] = 0;
  __syncthreads();
  int e0 = blockIdx.x * 4096 + tid;
#pragma unroll
  for (int j = 0; j < 4; ++j) {
    int e = e0 + j * 1024;
    if (e < NE) atomicAdd(&lh[ecol[e] >> 8], 1);
  }
  __syncthreads();
  if (tid < NB && lh[tid] > 0) atomicAdd(&hist[tid], lh[tid]);
}

// ---------------- scan196: bucket bases, init cursors ----------------
__global__ __launch_bounds__(256) void scanb_k(const int* __restrict__ hist,
                                               int* __restrict__ ebase,
                                               int* __restrict__ cursor,
                                               int* __restrict__ csr_ptr) {
  __shared__ int sc[256];
  int t = threadIdx.x;
  int h = (t < NB) ? hist[t] : 0;
  sc[t] = h; __syncthreads();
  for (int off = 1; off < 256; off <<= 1) {
    int v = (t >= off) ? sc[t - off] : 0;
    __syncthreads();
    sc[t] += v;
    __syncthreads();
  }
  if (t < NB) { ebase[t] = sc[t] - h; cursor[t] = sc[t] - h; }
  if (t == NB - 1) ebase[NB] = sc[t];
  if (t == 0) csr_ptr[NN] = NE;
}

// ---------------- pass1b: place packed edges into bucket regions ----------------
__global__ __launch_bounds__(1024) void p1b_k(const int* __restrict__ erow,
                                              const int* __restrict__ ecol,
                                              int* __restrict__ cursor,
                                              unsigned int* __restrict__ ebuf) {
  __shared__ int lcnt[NB], gb[NB];
  int tid = threadIdx.x;
  if (tid < NB) lcnt[tid] = 0;
  __syncthreads();
  int e0 = blockIdx.x * 4096 + tid;
  int bk[4], sl[4]; unsigned int pk[4];
#pragma unroll
  for (int j = 0; j < 4; ++j) {
    int e = e0 + j * 1024;
    bk[j] = -1;
    if (e < NE) {
      int d = ecol[e], s = erow[e];
      bk[j] = d >> 8;
      pk[j] = ((unsigned int)(d & 255) << 16) | (unsigned int)s;
      sl[j] = atomicAdd(&lcnt[bk[j]], 1);
    }
  }
  __syncthreads();
  if (tid < NB) {
    int c = lcnt[tid];
    gb[tid] = c ? atomicAdd(&cursor[tid], c) : 0;
  }
  __syncthreads();
#pragma unroll
  for (int j = 0; j < 4; ++j)
    if (bk[j] >= 0) ebuf[gb[bk[j]] + sl[j]] = pk[j];
}

// ---------------- pass2: per-bucket counting sort + dinv + x->bf16*dinv ----------------
__global__ __launch_bounds__(1024) void p2_k(const unsigned int* __restrict__ ebuf,
                                             const int* __restrict__ ebase,
                                             const float* __restrict__ x,
                                             int* __restrict__ csr_ptr,
                                             int* __restrict__ csr_src,
                                             float* __restrict__ dinv,
                                             unsigned short* __restrict__ xb) {
  __shared__ unsigned int pr[BCAP];
  __shared__ int srcb[BCAP];
  __shared__ int hist_s[256], scn[256], lcur[256];
  __shared__ float dinv_s[256];
  int b = blockIdx.x, tid = threadIdx.x;
  int beg = ebase[b];
  int cnt = ebase[b + 1] - beg;
  if (cnt > BCAP) cnt = BCAP;   // safety clamp (never hit for this dataset)

  if (tid < 256) hist_s[tid] = 0;
  __syncthreads();
  for (int i = tid; i < cnt; i += 1024) {
    unsigned int p = ebuf[beg + i];
    pr[i] = p;
    atomicAdd(&hist_s[p >> 16], 1);
  }
  __syncthreads();
  if (tid < 256) scn[tid] = hist_s[tid];
  __syncthreads();
  for (int off = 1; off < 256; off <<= 1) {
    int v = (tid < 256 && tid >= off) ? scn[tid - off] : 0;
    __syncthreads();
    if (tid < 256) scn[tid] += v;
    __syncthreads();
  }
  if (tid < 256) {
    int ex = scn[tid] - hist_s[tid];
    lcur[tid] = ex;
    int V = b * 256 + tid;
    if (V < NN) {
      csr_ptr[V] = beg + ex;
      float dv = rsqrtf((float)(hist_s[tid] + 1));
      dinv[V] = dv;
      dinv_s[tid] = dv;
    }
  }
  __syncthreads();
  for (int i = tid; i < cnt; i += 1024) {
    unsigned int p = pr[i];
    int pos = atomicAdd(&lcur[p >> 16], 1);
    srcb[pos] = (int)(p & 0xFFFFu);
  }
  __syncthreads();
  for (int i = tid; i < cnt; i += 1024) csr_src[beg + i] = srcb[i];

  // x -> bf16 pre-scaled by dinv for this bucket's nodes
  for (int i4 = tid; i4 < 256 * 32; i4 += 1024) {
    int vl = i4 >> 5;
    int V = b * 256 + vl;
    if (V < NN) {
      float d = dinv_s[vl];
      f32x4 vx = *((const f32x4*)(x + (size_t)V * DD) + (i4 & 31));
      uint2 o;
      o.x = pack2(vx[0] * d, vx[1] * d);
      o.y = pack2(vx[2] * d, vx[3] * d);
      *((uint2*)(xb + (size_t)V * DD) + (i4 & 31)) = o;
    }
  }
}

// ---------------- gptr: graph boundaries from sorted batch ----------------
__global__ void gptr_k(const int* __restrict__ batch, int* __restrict__ gptr) {
  int i = blockIdx.x * 256 + threadIdx.x;
  if (i >= NN) return;
  int b  = batch[i];
  int bp = (i == 0) ? -1 : batch[i - 1];
  for (int g = bp + 1; g <= b; ++g) gptr[g] = i;
  if (i == NN - 1) { for (int g = b + 1; g <= NG; ++g) gptr[g] = NN; }
}

// ---------------- aggregation: agg[v] = dinv_v * (hs_v + sum_{s in N(v)} hs_s) ----------------
// hs pre-scaled by dinv. One wave/node; quarter-wave (16 lanes x 16B) per edge,
// 4-way unrolled -> 16 outstanding row gathers per wave. fp32 accum. Zero LDS.
__global__ __launch_bounds__(256) void agg_k(const unsigned short* __restrict__ hs,
                                             unsigned short* __restrict__ agg,
                                             const int* __restrict__ csr_ptr,
                                             const int* __restrict__ csr_src,
                                             const float* __restrict__ dinv) {
  int v = blockIdx.x * 4 + (threadIdx.x >> 6);
  if (v >= NN) return;
  int lane = threadIdx.x & 63;
  int qg = lane >> 4, r = lane & 15;
  const uint4* rows = (const uint4*)hs;   // row v = rows[v*16 + r]

  float a[8] = {0.f, 0.f, 0.f, 0.f, 0.f, 0.f, 0.f, 0.f};
  float b[8] = {0.f, 0.f, 0.f, 0.f, 0.f, 0.f, 0.f, 0.f};
  if (qg == 0) acc8(a, rows[(size_t)v * 16 + r]);   // self term

  int e = csr_ptr[v] + qg, end = csr_ptr[v + 1];
  // 4-way unroll: 4 independent gathers in flight per lane
  for (; e + 12 < end; e += 16) {
    int s0 = csr_src[e];
    int s1 = csr_src[e + 4];
    int s2 = csr_src[e + 8];
    int s3 = csr_src[e + 12];
    uint4 p0 = rows[(size_t)s0 * 16 + r];
    uint4 p1 = rows[(size_t)s1 * 16 + r];
    uint4 p2 = rows[(size_t)s2 * 16 + r];
    uint4 p3 = rows[(size_t)s3 * 16 + r];
    acc8(a, p0); acc8(b, p1); acc8(a, p2); acc8(b, p3);
  }
  // 2-way tail
  for (; e + 4 < end; e += 8) {
    int s0 = csr_src[e];
    int s1 = csr_src[e + 4];
    uint4 p0 = rows[(size_t)s0 * 16 + r];
    uint4 p1 = rows[(size_t)s1 * 16 + r];
    acc8(a, p0); acc8(b, p1);
  }
  if (e < end) acc8(a, rows[(size_t)csr_src[e] * 16 + r]);

#pragma unroll
  for (int t = 0; t < 8; ++t) a[t] += b[t];

#pragma unroll
  for (int t = 0; t < 8; ++t) {
    a[t] += __shfl_xor(a[t], 16, 64);
    a[t] += __shfl_xor(a[t], 32, 64);
  }

  if (qg == 0) {
    float dv = dinv[v];
    uint4 o;
    o.x = pack2(dv * a[0], dv * a[1]);
    o.y = pack2(dv * a[2], dv * a[3]);
    o.z = pack2(dv * a[4], dv * a[5]);
    o.w = pack2(dv * a[6], dv * a[7]);
    *((uint4*)(agg + (size_t)v * DD) + r) = o;
  }
}

// ---------------- fused GEMM: out = relu(A @ W + b) [optionally * dinv], bf16 out ----------------
__global__ __launch_bounds__(256) void gemm_relu_k(const unsigned short* __restrict__ A,
                                                   const float* __restrict__ W,
                                                   const float* __restrict__ bias,
                                                   unsigned short* __restrict__ out,
                                                   const float* __restrict__ dscale,
                                                   int M) {
  __shared__ unsigned short Wt[128][136];   // transposed W (bf16), +8 pad
  int tid = threadIdx.x;
  for (int i = tid; i < 128 * 128; i += 256) {
    int k = i >> 7, n = i & 127;
    Wt[n][k] = f2bf(W[i]);
  }
  __syncthreads();

  int wave = tid >> 6, lane = tid & 63;
  int q = lane >> 4, r = lane & 15;
  int row0 = blockIdx.x * 64 + wave * 16;

  int arow = row0 + r;
  if (arow > M - 1) arow = M - 1;
  const short* Arow = (const short*)A + (size_t)arow * DD;

  short8 afrag[4];
#pragma unroll
  for (int ks = 0; ks < 4; ++ks)
    afrag[ks] = *(const short8*)(Arow + ks * 32 + q * 8);

  f32x4 acc[8];
#pragma unroll
  for (int ct = 0; ct < 8; ++ct) acc[ct] = (f32x4){0.f, 0.f, 0.f, 0.f};

#pragma unroll
  for (int ks = 0; ks < 4; ++ks) {
#pragma unroll
    for (int ct = 0; ct < 8; ++ct) {
      short8 bfrag = *(const short8*)(&Wt[ct * 16 + r][ks * 32 + q * 8]);
      acc[ct] = __builtin_amdgcn_mfma_f32_16x16x32_bf16(afrag[ks], bfrag, acc[ct], 0, 0, 0);
    }
  }

  int orow = row0 + q * 4;
  float sc[4];
#pragma unroll
  for (int reg = 0; reg < 4; ++reg) {
    int rr = orow + reg;
    sc[reg] = (dscale && rr < M) ? dscale[rr] : 1.f;
  }
#pragma unroll
  for (int ct = 0; ct < 8; ++ct) {
    int coln = ct * 16 + r;
    float bc = bias[coln];
#pragma unroll
    for (int reg = 0; reg < 4; ++reg) {
      int rr = orow + reg;
      if (rr < M) {
        float val = fmaxf(acc[ct][reg] + bc, 0.f) * sc[reg];
        out[(size_t)rr * DD + coln] = f2bf(val);
      }
    }
  }
}

// ---------------- pooling ----------------
__global__ __launch_bounds__(128) void pool_k(const unsigned short* __restrict__ h,
                                              const int* __restrict__ gptr,
                                              float* __restrict__ gpool) {
  int g = blockIdx.x, t = threadIdx.x;
  int beg = gptr[g], end = gptr[g + 1];
  float acc = 0.f;
  for (int v = beg; v < end; ++v) acc += bf2f(h[(size_t)v * DD + t]);
  gpool[g * DD + t] = acc;
}

// ---------------- MLP head ----------------
__global__ __launch_bounds__(128) void mlp_k(const float* __restrict__ gpool,
                                             const float* __restrict__ W1,
                                             const float* __restrict__ b1,
                                             const float* __restrict__ W2,
                                             const float* __restrict__ b2,
                                             const float* __restrict__ W3,
                                             const float* __restrict__ b3,
                                             float* __restrict__ out) {
  __shared__ float s_g[128], s_h1[128], s_h2[64];
  int g = blockIdx.x, t = threadIdx.x;
  s_g[t] = gpool[g * DD + t];
  __syncthreads();
  {
    float a = b1[t];
    for (int k = 0; k < 128; ++k) a += s_g[k] * W1[k * 128 + t];
    s_h1[t] = fmaxf(a, 0.f);
  }
  __syncthreads();
  if (t < 64) {
    float a = b2[t];
    for (int k = 0; k < 128; ++k) a += s_h1[k] * W2[k * 64 + t];
    s_h2[t] = fmaxf(a, 0.f);
  }
  __syncthreads();
  if (t < NC) {
    float a = b3[t];
    for (int k = 0; k < 64; ++k) a += s_h2[k] * W3[k * NC + t];
    out[g * NC + t] = a;
  }
}

// ---------------- launch ----------------

extern "C" void kernel_launch(void* const* d_in, const int* in_sizes, int n_in,
                              void* d_out, int out_size, void* d_ws, size_t ws_size,
                              hipStream_t stream) {
  const float* x     = (const float*)d_in[0];
  const int*   ei    = (const int*)d_in[1];
  const int*   batch = (const int*)d_in[2];
  const float* Wc    = (const float*)d_in[3];
  const float* bc    = (const float*)d_in[4];
  const float* W1    = (const float*)d_in[5];
  const float* b1    = (const float*)d_in[6];
  const float* W2    = (const float*)d_in[7];
  const float* b2    = (const float*)d_in[8];
  const float* W3    = (const float*)d_in[9];
  const float* b3    = (const float*)d_in[10];
  float* out = (float*)d_out;

  const int* erow = ei;        // edge_index[0] (source)
  const int* ecol = ei + NE;   // edge_index[1] (dest)

  char* w = (char*)d_ws;
  int*   hist    = (int*)w;    w += NB * 4;          // memset 0
  int*   cursor  = (int*)w;    w += NB * 4;          // memset 0 (overwritten by scanb)
  int*   ebase   = (int*)w;    w += (NB + 4) * 4;
  int*   csr_ptr = (int*)w;    w += (size_t)(NN + 4) * 4;
  int*   gptr    = (int*)w;    w += (NG + 4) * 4;
  int*   csr_src = (int*)w;    w += (size_t)NE * 4;
  float* dinv    = (float*)w;  w += (size_t)NN * 4;
  float* gpool   = (float*)w;  w += (size_t)NG * DD * 4;
  w = (char*)(((uintptr_t)w + 255) & ~(uintptr_t)255);
  unsigned short* xb   = (unsigned short*)w; w += (size_t)NN * DD * 2;
  unsigned short* aggb = (unsigned short*)w; w += (size_t)NN * DD * 2;
  unsigned short* hbuf = (unsigned short*)w; w += (size_t)NN * DD * 2;
  unsigned int* ebuf = (unsigned int*)aggb;  // alias: ebuf only live during preproc

  hipMemsetAsync(d_ws, 0, NB * 2 * 4, stream);   // hist + cursor

  p1a_k  <<<NB, 1024, 0, stream>>>(ecol, hist);
  scanb_k<<<1, 256, 0, stream>>>(hist, ebase, cursor, csr_ptr);
  p1b_k  <<<NB, 1024, 0, stream>>>(erow, ecol, cursor, ebuf);
  p2_k   <<<NB, 1024, 0, stream>>>(ebuf, ebase, x, csr_ptr, csr_src, dinv, xb);
  gptr_k <<<(NN + 255) / 256, 256, 0, stream>>>(batch, gptr);

  const int aggGrid  = (NN + 3) / 4;
  const int gemmGrid = (NN + 63) / 64;

  for (int l = 0; l < NL; ++l) {
    const unsigned short* hin = (l == 0) ? xb : hbuf;
    const float* dsc = (l == NL - 1) ? nullptr : dinv;
    agg_k<<<aggGrid, 256, 0, stream>>>(hin, aggb, csr_ptr, csr_src, dinv);
    gemm_relu_k<<<gemmGrid, 256, 0, stream>>>(aggb, Wc + (size_t)l * DD * DD,
                                              bc + (size_t)l * DD, hbuf, dsc, NN);
  }

  pool_k<<<NG, 128, 0, stream>>>(hbuf, gptr, gpool);
  mlp_k <<<NG, 128, 0, stream>>>(gpool, W1, b1, W2, b2, W3, b3, out);

  (void)in_sizes; (void)n_in; (void)out_size; (void)ws_size;
}